// Round 1
// baseline (240.039 us; speedup 1.0000x reference)
//
#include <hip/hip_runtime.h>

#define NUM_SEGS 1024
#define CHUNK_LOG 13
#define CHUNK (1 << CHUNK_LOG)   // 8192 elements per chunk
#define SUBCH 4                  // chunks per block (superchunk = 32768)
#define SUPER (CHUNK * SUBCH)
#define BLK 1024                 // 16 waves/block; grid 512 -> 2 blocks/CU = 32 waves/CU
#define NWAVE (BLK / 64)
#define SEGBLK 256

__device__ __forceinline__ float waveReduceSumF(float v) {
#pragma unroll
    for (int off = 32; off > 0; off >>= 1) v += __shfl_down(v, off, 64);
    return v;
}
__device__ __forceinline__ double waveReduceSumD(double v) {
#pragma unroll
    for (int off = 32; off > 0; off >>= 1) v += __shfl_down(v, off, 64);
    return v;
}
__device__ __forceinline__ unsigned waveReduceSumU(unsigned v) {
#pragma unroll
    for (int off = 32; off > 0; off >>= 1) v += __shfl_down(v, off, 64);
    return v;
}
__device__ __forceinline__ int waveReduceMaxI(int v) {
#pragma unroll
    for (int off = 32; off > 0; off >>= 1) {
        const int o = __shfl_down(v, off, 64);
        v = o > v ? o : v;
    }
    return v;
}

// ---------------- init: zero accumulators (ws is poisoned 0xAA every call) ---
__global__ void init_kernel(unsigned* __restrict__ seg_cnt,
                            int* __restrict__ last_chunk,
                            unsigned* __restrict__ obs,
                            double* __restrict__ loss1,
                            double* __restrict__ loss2,
                            unsigned* __restrict__ done) {
    const int t = blockIdx.x * blockDim.x + threadIdx.x;
    if (t < NUM_SEGS) { seg_cnt[t] = 0u; last_chunk[t] = -1; }
    if (t == 0) { obs[0] = 0u; loss1[0] = 0.0; loss2[0] = 0.0; done[0] = 0u; }
}

// ---------------- pass 1: chunk exp-sums, per-seg presence & count, E stats --
// atomicMax(last index) is GONE: per-chunk presence via plain LDS byte stores
// (benign races: same value within a chunk; chunk order enforced by barrier).
__global__ __launch_bounds__(BLK, 8) void pass1_kernel(
    const float* __restrict__ outs, const int* __restrict__ te,
    const int* __restrict__ tt, int N, int nChunks,
    float* __restrict__ chunk_sums, unsigned* __restrict__ seg_cnt,
    int* __restrict__ last_chunk, unsigned* __restrict__ obs,
    double* __restrict__ loss1) {
    __shared__ unsigned hist[NUM_SEGS];
    __shared__ unsigned char flags[NUM_SEGS];  // last sub-chunk (0..SUBCH-1) seen, 0xFF = none
    __shared__ float redF[NWAVE];
    __shared__ unsigned redU[NWAVE];

    for (int t = threadIdx.x; t < NUM_SEGS; t += BLK) hist[t] = 0u;
    if (threadIdx.x < NUM_SEGS / 4)
        reinterpret_cast<unsigned*>(flags)[threadIdx.x] = 0xFFFFFFFFu;
    __syncthreads();

    float sumOE = 0.f;
    unsigned cntE = 0u;
    const int superBase = blockIdx.x * SUPER;
    const int lane = threadIdx.x & 63;
    const int wid = threadIdx.x >> 6;

#pragma unroll 1
    for (int k = 0; k < SUBCH; ++k) {
        const int cbase = superBase + k * CHUNK;
        float sumExp = 0.f;
        if (cbase + CHUNK <= N) {
            // fast path: full chunk, float4/int4 coalesced (2 iters at BLK=1024)
#pragma unroll
            for (int it = 0; it < CHUNK / (BLK * 4); ++it) {
                const int i = cbase + it * (BLK * 4) + (threadIdx.x << 2);
                const float4 o = *reinterpret_cast<const float4*>(outs + i);
                const int4 ev = *reinterpret_cast<const int4*>(te + i);
                const int4 sv = *reinterpret_cast<const int4*>(tt + i);
                const float e0 = __expf(o.x), e1 = __expf(o.y);
                const float e2 = __expf(o.z), e3 = __expf(o.w);
                sumExp += (e0 + e1) + (e2 + e3);
                const int s0 = sv.x < 0 ? -sv.x : sv.x;
                const int s1 = sv.y < 0 ? -sv.y : sv.y;
                const int s2 = sv.z < 0 ? -sv.z : sv.z;
                const int s3 = sv.w < 0 ? -sv.w : sv.w;
                flags[s0] = (unsigned char)k;
                flags[s1] = (unsigned char)k;
                flags[s2] = (unsigned char)k;
                flags[s3] = (unsigned char)k;
                if (ev.x > 0) { cntE++; sumOE += o.x; atomicAdd(&hist[s0], 1u); }
                if (ev.y > 0) { cntE++; sumOE += o.y; atomicAdd(&hist[s1], 1u); }
                if (ev.z > 0) { cntE++; sumOE += o.z; atomicAdd(&hist[s2], 1u); }
                if (ev.w > 0) { cntE++; sumOE += o.w; atomicAdd(&hist[s3], 1u); }
            }
        } else {
            // tail path (not hit for N = 16M)
            const int end = (cbase + CHUNK < N) ? cbase + CHUNK : N;
            for (int i = cbase + (int)threadIdx.x; i < end; i += BLK) {
                const float o = outs[i];
                const int e = te[i];
                int s = tt[i]; s = s < 0 ? -s : s;
                sumExp += __expf(o);
                flags[s] = (unsigned char)k;
                if (e > 0) { cntE++; sumOE += o; atomicAdd(&hist[s], 1u); }
            }
        }
        // block-reduce this chunk's exp-sum; barrier also orders flags writes
        const float w = waveReduceSumF(sumExp);
        if (lane == 0) redF[wid] = w;
        __syncthreads();
        if (threadIdx.x == 0) {
            float s4 = 0.f;
#pragma unroll
            for (int j = 0; j < NWAVE; ++j) s4 += redF[j];
            const int cidx = cbase >> CHUNK_LOG;
            if (cidx < nChunks) chunk_sums[cidx] = s4;
        }
        __syncthreads();
    }

    // flush per-block histogram / presence to global
    const int chunk0 = blockIdx.x * SUBCH;
    for (int t = threadIdx.x; t < NUM_SEGS; t += BLK) {
        const unsigned h = hist[t];
        if (h) atomicAdd(&seg_cnt[t], h);
        const unsigned f = flags[t];
        if (f != 0xFFu) atomicMax(&last_chunk[t], chunk0 + (int)f);
    }

    // block-reduce E stats
    const float wOE = waveReduceSumF(sumOE);
    const unsigned wC = waveReduceSumU(cntE);
    if (lane == 0) { redF[wid] = wOE; redU[wid] = wC; }
    __syncthreads();
    if (threadIdx.x == 0) {
        float oe = 0.f; unsigned c = 0u;
#pragma unroll
        for (int j = 0; j < NWAVE; ++j) { oe += redF[j]; c += redU[j]; }
        atomicAdd(loss1, (double)oe);
        atomicAdd(obs, c);
    }
}

// ---------------- pass 2 (fused): per-segment prefix + last-idx + V*cnt + final
// Each block: fp64 prefix over csums[0..lc) (L2-hot, 8KB), find exact last
// index of its segment inside chunk lc, fp32 exp-sum to it, then V*cnt.
// Last block through the ticket computes the output (no separate final kernel).
__global__ __launch_bounds__(SEGBLK) void seg_final_kernel(
    const float* __restrict__ outs, const int* __restrict__ tt,
    const float* __restrict__ csums, const unsigned* __restrict__ seg_cnt,
    const int* __restrict__ last_chunk, const double* __restrict__ loss1,
    double* __restrict__ loss2, const unsigned* __restrict__ obs,
    unsigned* __restrict__ done, float* __restrict__ out, int N) {
    __shared__ double redD[SEGBLK / 64];
    __shared__ float redF[SEGBLK / 64];
    __shared__ int redI[SEGBLK / 64];
    __shared__ int s_li;

    const int t = blockIdx.x;
    const unsigned cnt = seg_cnt[t];
    const int lane = threadIdx.x & 63, wid = threadIdx.x >> 6;

    if (cnt != 0u) {  // cnt==0 segments contribute 0 (matches jnp.maximum/seg empty)
        const int lc = last_chunk[t];  // >=0 whenever cnt>0
        // fp64 exclusive prefix of chunk sums [0, lc)
        double p = 0.0;
        for (int c = threadIdx.x; c < lc; c += SEGBLK) p += (double)csums[c];
        p = waveReduceSumD(p);
        if (lane == 0) redD[wid] = p;

        // find the exact last index of segment t inside chunk lc
        const int base = lc << CHUNK_LOG;
        const int end = (base + CHUNK < N) ? base + CHUNK : N;
        int li = -1;
        for (int i = base + (int)threadIdx.x; i < end; i += SEGBLK) {
            int s = tt[i]; s = s < 0 ? -s : s;
            if (s == t) li = i;  // strided increasing: last assignment is this thread's max
        }
        li = waveReduceMaxI(li);
        if (lane == 0) redI[wid] = li;
        __syncthreads();
        if (threadIdx.x == 0) {
            int m = redI[0];
#pragma unroll
            for (int j = 1; j < SEGBLK / 64; ++j) m = redI[j] > m ? redI[j] : m;
            s_li = m;
        }
        __syncthreads();
        const int LI = s_li;

        // fp32 in-chunk exp-sum up to and including LI (monotone cumsum => max at LI)
        float fs = 0.f;
        for (int i = base + (int)threadIdx.x; i <= LI; i += SEGBLK) fs += __expf(outs[i]);
        fs = waveReduceSumF(fs);
        if (lane == 0) redF[wid] = fs;
        __syncthreads();
        if (threadIdx.x == 0 && LI >= 0) {
            double pre = 0.0;
            float fsum = 0.f;
#pragma unroll
            for (int j = 0; j < SEGBLK / 64; ++j) { pre += redD[j]; fsum += redF[j]; }
            double sm = log(pre + (double)fsum);
            if (sm < 0.0) sm = 0.0;  // jnp.maximum(..., 0.0)
            atomicAdd(loss2, sm * (double)cnt);
        }
    }

    // done-ticket: last block finalizes
    if (threadIdx.x == 0) {
        __threadfence();
        const unsigned d = atomicAdd(done, 1u);
        if (d == (unsigned)(gridDim.x - 1)) {
            const double l2 = atomicAdd(loss2, 0.0);  // atomic read (L2-coherent)
            const double l1 = loss1[0];               // written by prior dispatch
            const unsigned o = obs[0];
            out[0] = (float)((l2 - l1) / (double)o);
        }
    }
}

extern "C" void kernel_launch(void* const* d_in, const int* in_sizes, int n_in,
                              void* d_out, int out_size, void* d_ws, size_t ws_size,
                              hipStream_t stream) {
    const float* outs = (const float*)d_in[0];
    const int* te = (const int*)d_in[1];
    const int* tt = (const int*)d_in[2];
    const int N = in_sizes[0];
    float* out = (float*)d_out;

    const int nChunks = (N + CHUNK - 1) / CHUNK;

    char* ws = (char*)d_ws;
    double* d_loss1 = (double*)ws;                        // 1 double
    double* d_loss2 = d_loss1 + 1;                        // 1 double
    float* d_csums = (float*)(ws + 16);                   // nChunks floats
    unsigned* d_segcnt = (unsigned*)(d_csums + nChunks);  // NUM_SEGS u32
    int* d_lastchunk = (int*)(d_segcnt + NUM_SEGS);       // NUM_SEGS int
    unsigned* d_obs = (unsigned*)(d_lastchunk + NUM_SEGS);
    unsigned* d_done = d_obs + 1;

    init_kernel<<<(NUM_SEGS + 255) / 256, 256, 0, stream>>>(
        d_segcnt, d_lastchunk, d_obs, d_loss1, d_loss2, d_done);
    const int nSuper = (N + SUPER - 1) / SUPER;
    pass1_kernel<<<nSuper, BLK, 0, stream>>>(outs, te, tt, N, nChunks, d_csums,
                                             d_segcnt, d_lastchunk, d_obs, d_loss1);
    seg_final_kernel<<<NUM_SEGS, SEGBLK, 0, stream>>>(
        outs, tt, d_csums, d_segcnt, d_lastchunk, d_loss1, d_loss2, d_obs, d_done,
        out, N);
}